// Round 8
// baseline (258.763 us; speedup 1.0000x reference)
//
#include <hip/hip_runtime.h>
#include <math.h>

#define N 512
#define NN (N * N)
#define C 16
#define K 262144
#define LOG2N 9
#define NCOL 8

typedef float f4 __attribute__((ext_vector_type(4)));

// ============ phase 1: bin points by cell (counting sort, no fp atomics) ============

// prep + histogram fused: cell index, sign-folded dcf, count per cell
__global__ __launch_bounds__(256) void prep_hist_kernel(const float2* __restrict__ traj,
                                                        const float* __restrict__ dcf,
                                                        int* __restrict__ cell,
                                                        float* __restrict__ sdcf,
                                                        int* __restrict__ count) {
    int k = blockIdx.x * 256 + threadIdx.x;
    float2 t = traj[k];
    // jnp.round is half-to-even; __float2int_rn matches.
    int iy = __float2int_rn((t.x + 0.5f) * (float)N) & (N - 1);
    int ix = __float2int_rn((t.y + 0.5f) * (float)N) & (N - 1);
    int cl = iy * N + ix;
    cell[k] = cl;
    float s = ((iy + ix) & 1) ? -1.0f : 1.0f;   // ifftshift folded into input sign
    sdcf[k] = dcf[k] * s;
    atomicAdd(&count[cl], 1);                    // avg 1 pt/cell -> low contention
}

// per-block reduce: 256 blocks x 1024 ints -> bsum[256]
__global__ __launch_bounds__(256) void scan_reduce_kernel(const int* __restrict__ count,
                                                          int* __restrict__ bsum) {
    __shared__ int sd[256];
    int t = threadIdx.x;
    const int4* c4 = (const int4*)count;
    int4 v = c4[blockIdx.x * 256 + t];
    sd[t] = v.x + v.y + v.z + v.w;
    __syncthreads();
    for (int d = 128; d > 0; d >>= 1) {
        if (t < d) sd[t] += sd[t + d];
        __syncthreads();
    }
    if (t == 0) bsum[blockIdx.x] = sd[0];
}

// single block: exclusive scan of bsum[256] -> boffs[256]; also offs[NN] = K
__global__ __launch_bounds__(256) void scan_top_kernel(const int* __restrict__ bsum,
                                                       int* __restrict__ boffs,
                                                       int* __restrict__ offs) {
    __shared__ int sd[256];
    int t = threadIdx.x;
    int v = bsum[t];
    sd[t] = v;
    __syncthreads();
    for (int d = 1; d < 256; d <<= 1) {
        int tmp = (t >= d) ? sd[t - d] : 0;
        __syncthreads();
        sd[t] += tmp;
        __syncthreads();
    }
    boffs[t] = sd[t] - v;   // exclusive
    if (t == 0) offs[NN] = K;
}

// per-block exclusive scan: offs[i] = global exclusive prefix; cursor = copy of offs
__global__ __launch_bounds__(256) void scan_final_kernel(const int* __restrict__ count,
                                                         const int* __restrict__ boffs,
                                                         int* __restrict__ offs,
                                                         int* __restrict__ cursor) {
    __shared__ int sd[256];
    int t = threadIdx.x;
    int base_idx = blockIdx.x * 256 + t;
    const int4* c4 = (const int4*)count;
    int4 v = c4[base_idx];
    int s = v.x + v.y + v.z + v.w;
    sd[t] = s;
    __syncthreads();
    for (int d = 1; d < 256; d <<= 1) {
        int tmp = (t >= d) ? sd[t - d] : 0;
        __syncthreads();
        sd[t] += tmp;
        __syncthreads();
    }
    int base = boffs[blockIdx.x] + sd[t] - s;    // global exclusive prefix for this thread's 4
    int4 o;
    o.x = base;
    o.y = base + v.x;
    o.z = base + v.x + v.y;
    o.w = base + v.x + v.y + v.z;
    ((int4*)offs)[base_idx] = o;
    ((int4*)cursor)[base_idx] = o;
}

// place: each point claims a unique sorted slot p and writes a FULL-CHANNEL
// pre-weighted payload record pxv[p][c] = w*x[c][k] (128 B = 2 full cache lines,
// scattered but no write amplification) + pre-bit-reversed column pcol[p].
// This moves ALL randomness out of the hot gather: build_rowfft then streams
// its slice perfectly coalesced.
__global__ __launch_bounds__(256) void place_kernel(const int* __restrict__ cell,
                                                    const float* __restrict__ sdcf,
                                                    int* __restrict__ cursor,
                                                    int* __restrict__ pcol,
                                                    float2* __restrict__ pxv,
                                                    const float* __restrict__ xr,
                                                    const float* __restrict__ xi) {
    int k = blockIdx.x * 256 + threadIdx.x;
    int cl = cell[k];
    float w = sdcf[k];
    int p = atomicAdd(&cursor[cl], 1);
    int col = cl & (N - 1);
    pcol[p] = (int)(__brev((unsigned)col) >> (32 - LOG2N));   // bit-reversed col
    float2* rec = pxv + (size_t)p * C;
#pragma unroll
    for (int c = 0; c < C; ++c) {
        rec[c] = make_float2(xr[(size_t)c * K + k] * w, xi[(size_t)c * K + k] * w);
    }
}

// ============ fused grid-build + row FFT ============
// block = (row r, channel-group cg). blockIdx = r*8+cg -> XCD = cg.
// Gather phase is now pure streaming: per point one coalesced 4 B pcol load +
// one 16 B payload slice (this cg's 2 channels), scattered into LDS at the
// pre-bit-reversed column with ds_add — no random global reads, no FMA.
__global__ __launch_bounds__(256) void build_rowfft_kernel(const int* __restrict__ offs,
                                                           const int* __restrict__ pcol,
                                                           const float2* __restrict__ pxv,
                                                           float2* __restrict__ grid) {
    __shared__ float sr0[N], si0[N], sr1[N], si1[N];
    int b = blockIdx.x;
    int cg = b & 7;
    int r = b >> 3;
    int c0 = cg * 2;
    int t = threadIdx.x;

    for (int i = t; i < N; i += 256) { sr0[i] = 0.f; si0[i] = 0.f; sr1[i] = 0.f; si1[i] = 0.f; }
    int start = offs[r * N];
    int end   = offs[r * N + N];   // r=511 uses offs[NN]=K
    __syncthreads();

    // point-parallel streaming scatter: ~512 points per row, 2 rounds of 256 lanes
    for (int p = start + t; p < end; p += 256) {
        int bc = pcol[p];
        f4 v = __builtin_nontemporal_load((const f4*)(pxv + (size_t)p * C + c0));
        atomicAdd(&sr0[bc], v.x);
        atomicAdd(&si0[bc], v.y);
        atomicAdd(&sr1[bc], v.z);
        atomicAdd(&si1[bc], v.w);
    }
    __syncthreads();

    // 9 radix-2 DIT stages, +i exponent; input already bit-reversed, output natural
    for (int s = 1; s <= LOG2N; ++s) {
        int half = 1 << (s - 1);
        int m = half << 1;
        int j = t & (half - 1);
        int grp = t >> (s - 1);
        int p1 = grp * m + j;
        int p2 = p1 + half;
        float ang = 6.283185307179586f * (float)j / (float)m;
        float sn, cs;
        __sincosf(ang, &sn, &cs);
        float x2, y2, tr, ti, ur, ui;
        x2 = sr0[p2]; y2 = si0[p2];
        tr = cs * x2 - sn * y2; ti = cs * y2 + sn * x2;
        ur = sr0[p1]; ui = si0[p1];
        sr0[p2] = ur - tr; si0[p2] = ui - ti;
        sr0[p1] = ur + tr; si0[p1] = ui + ti;
        x2 = sr1[p2]; y2 = si1[p2];
        tr = cs * x2 - sn * y2; ti = cs * y2 + sn * x2;
        ur = sr1[p1]; ui = si1[p1];
        sr1[p2] = ur - tr; si1[p2] = ui - ti;
        sr1[p1] = ur + tr; si1[p1] = ui + ti;
        __syncthreads();
    }

    float2* g0 = grid + (size_t)c0 * NN + (size_t)r * N;
    float2* g1 = grid + (size_t)(c0 + 1) * NN + (size_t)r * N;
    for (int i = t; i < N; i += 256) {
        g0[i] = make_float2(sr0[i], si0[i]);
        g1[i] = make_float2(sr1[i], si1[i]);
    }
}

// ============ column FFT: NCOL columns per block through LDS ============
__global__ __launch_bounds__(256) void colfft_kernel(float2* __restrict__ grid) {
    __shared__ float sr[N * NCOL];
    __shared__ float si[N * NCOL];
    int blk = blockIdx.x;                        // c * (N/NCOL) + cg
    int c = blk >> 6;
    int cg = blk & 63;
    float2* base = grid + (size_t)c * NN + cg * NCOL;
    int t = threadIdx.x;

    for (int e = t; e < N * NCOL; e += 256) {
        int row = e >> 3, col = e & 7;
        float2 v = base[(size_t)row * N + col];
        sr[e] = v.x; si[e] = v.y;
    }
    __syncthreads();

    int col = t & 7;
    int tg = t >> 3;
    for (int i = tg; i < N; i += 32) {
        int j = __brev((unsigned)i) >> (32 - LOG2N);
        if (j > i) {
            int a1 = i * NCOL + col, a2 = j * NCOL + col;
            float a = sr[a1]; sr[a1] = sr[a2]; sr[a2] = a;
            float b = si[a1]; si[a1] = si[a2]; si[a2] = b;
        }
    }
    __syncthreads();

    for (int s = 1; s <= LOG2N; ++s) {
        int half = 1 << (s - 1);
        int m = half << 1;
        for (int b = tg; b < 256; b += 32) {
            int j = b & (half - 1);
            int grp = b >> (s - 1);
            int p1 = grp * m + j;
            int p2 = p1 + half;
            float ang = 6.283185307179586f * (float)j / (float)m;
            float sn, cs;
            __sincosf(ang, &sn, &cs);
            int a1 = p1 * NCOL + col, a2 = p2 * NCOL + col;
            float xr2 = sr[a2], xi2 = si[a2];
            float tr = cs * xr2 - sn * xi2;
            float ti = cs * xi2 + sn * xr2;
            float ur = sr[a1], ui = si[a1];
            sr[a2] = ur - tr; si[a2] = ui - ti;
            sr[a1] = ur + tr; si[a1] = ui + ti;
        }
        __syncthreads();
    }

    for (int e = t; e < N * NCOL; e += 256) {
        int row = e >> 3, col2 = e & 7;
        base[(size_t)row * N + col2] = make_float2(sr[e], si[e]);
    }
}

// ============ combine: out = (-1)^(ny+nx) * sum_c conj(csm)*img ============
__global__ __launch_bounds__(256) void combine_kernel(const float* __restrict__ csr,
                                                      const float* __restrict__ csi,
                                                      const float2* __restrict__ grid,
                                                      float* __restrict__ out) {
    int pix = blockIdx.x * 256 + threadIdx.x;
    int ny = pix >> LOG2N, nx = pix & (N - 1);
    float ar = 0.f, ai = 0.f;
#pragma unroll
    for (int c = 0; c < C; ++c) {
        float2 uv = grid[(size_t)c * NN + pix];
        float a = csr[c * NN + pix];
        float b = csi[c * NN + pix];
        ar += a * uv.x + b * uv.y;
        ai += a * uv.y - b * uv.x;
    }
    float s = ((ny + nx) & 1) ? -1.f : 1.f;      // fftshift folded into output sign
    out[pix] = s * ar;
    out[NN + pix] = s * ai;
}

extern "C" void kernel_launch(void* const* d_in, const int* in_sizes, int n_in,
                              void* d_out, int out_size, void* d_ws, size_t ws_size,
                              hipStream_t stream) {
    const float* x_real   = (const float*)d_in[0];
    const float* x_imag   = (const float*)d_in[1];
    const float* csm_real = (const float*)d_in[2];
    const float* csm_imag = (const float*)d_in[3];
    const float2* traj    = (const float2*)d_in[4];
    const float* dcf      = (const float*)d_in[5];
    float* out = (float*)d_out;

    char* ws = (char*)d_ws;
    size_t o = 0;
    float* grid  = (float*)(ws + o); o += (size_t)C * NN * 2 * sizeof(float);  // 32 MB
    float2* pxv  = (float2*)(ws + o); o += (size_t)K * C * sizeof(float2);     // 32 MB
    int*   cell  = (int*)(ws + o);   o += (size_t)K * sizeof(int);             // 1 MB
    float* sdcf  = (float*)(ws + o); o += (size_t)K * sizeof(float);           // 1 MB
    int*   count = (int*)(ws + o);   o += (size_t)NN * sizeof(int);            // 1 MB
    int*   offs  = (int*)(ws + o);   o += ((size_t)NN + 4) * sizeof(int);      // 1 MB (+pad)
    int*   cursor= (int*)(ws + o);   o += (size_t)NN * sizeof(int);            // 1 MB
    int*   pcol  = (int*)(ws + o);   o += (size_t)K * sizeof(int);             // 1 MB
    int*   bsum  = (int*)(ws + o);   o += 256 * sizeof(int);
    int*   boffs = (int*)(ws + o);   o += 256 * sizeof(int);

    (void)hipMemsetAsync(count, 0, (size_t)NN * sizeof(int), stream);

    prep_hist_kernel<<<K / 256, 256, 0, stream>>>(traj, dcf, cell, sdcf, count);
    scan_reduce_kernel<<<256, 256, 0, stream>>>(count, bsum);
    scan_top_kernel<<<1, 256, 0, stream>>>(bsum, boffs, offs);
    scan_final_kernel<<<256, 256, 0, stream>>>(count, boffs, offs, cursor);
    place_kernel<<<K / 256, 256, 0, stream>>>(cell, sdcf, cursor, pcol, pxv, x_real, x_imag);
    build_rowfft_kernel<<<N * 8, 256, 0, stream>>>(offs, pcol, pxv, (float2*)grid);
    colfft_kernel<<<C * (N / NCOL), 256, 0, stream>>>((float2*)grid);
    combine_kernel<<<NN / 256, 256, 0, stream>>>(csm_real, csm_imag, (float2*)grid, out);
}

// Round 9
// 250.288 us; speedup vs baseline: 1.0339x; 1.0339x over previous
//
#include <hip/hip_runtime.h>
#include <math.h>

#define N 512
#define NN (N * N)
#define C 16
#define K 262144
#define LOG2N 9
#define NCOL 8

typedef float f4 __attribute__((ext_vector_type(4)));

// ============ phase 1: bin points by cell (counting sort, no fp atomics) ============

__global__ __launch_bounds__(256) void prep_hist_kernel(const float2* __restrict__ traj,
                                                        const float* __restrict__ dcf,
                                                        int* __restrict__ cell,
                                                        float* __restrict__ sdcf,
                                                        int* __restrict__ count) {
    int k = blockIdx.x * 256 + threadIdx.x;
    float2 t = traj[k];
    // jnp.round is half-to-even; __float2int_rn matches.
    int iy = __float2int_rn((t.x + 0.5f) * (float)N) & (N - 1);
    int ix = __float2int_rn((t.y + 0.5f) * (float)N) & (N - 1);
    int cl = iy * N + ix;
    cell[k] = cl;
    float s = ((iy + ix) & 1) ? -1.0f : 1.0f;   // ifftshift folded into input sign
    sdcf[k] = dcf[k] * s;
    atomicAdd(&count[cl], 1);                    // avg 1 pt/cell -> low contention
}

__global__ __launch_bounds__(256) void scan_reduce_kernel(const int* __restrict__ count,
                                                          int* __restrict__ bsum) {
    __shared__ int sd[256];
    int t = threadIdx.x;
    const int4* c4 = (const int4*)count;
    int4 v = c4[blockIdx.x * 256 + t];
    sd[t] = v.x + v.y + v.z + v.w;
    __syncthreads();
    for (int d = 128; d > 0; d >>= 1) {
        if (t < d) sd[t] += sd[t + d];
        __syncthreads();
    }
    if (t == 0) bsum[blockIdx.x] = sd[0];
}

__global__ __launch_bounds__(256) void scan_top_kernel(const int* __restrict__ bsum,
                                                       int* __restrict__ boffs,
                                                       int* __restrict__ offs) {
    __shared__ int sd[256];
    int t = threadIdx.x;
    int v = bsum[t];
    sd[t] = v;
    __syncthreads();
    for (int d = 1; d < 256; d <<= 1) {
        int tmp = (t >= d) ? sd[t - d] : 0;
        __syncthreads();
        sd[t] += tmp;
        __syncthreads();
    }
    boffs[t] = sd[t] - v;   // exclusive
    if (t == 0) offs[NN] = K;
}

__global__ __launch_bounds__(256) void scan_final_kernel(const int* __restrict__ count,
                                                         const int* __restrict__ boffs,
                                                         int* __restrict__ offs,
                                                         int* __restrict__ cursor) {
    __shared__ int sd[256];
    int t = threadIdx.x;
    int base_idx = blockIdx.x * 256 + t;
    const int4* c4 = (const int4*)count;
    int4 v = c4[base_idx];
    int s = v.x + v.y + v.z + v.w;
    sd[t] = s;
    __syncthreads();
    for (int d = 1; d < 256; d <<= 1) {
        int tmp = (t >= d) ? sd[t - d] : 0;
        __syncthreads();
        sd[t] += tmp;
        __syncthreads();
    }
    int base = boffs[blockIdx.x] + sd[t] - s;    // global exclusive prefix for this thread's 4
    int4 o;
    o.x = base;
    o.y = base + v.x;
    o.z = base + v.x + v.y;
    o.w = base + v.x + v.y + v.z;
    ((int4*)offs)[base_idx] = o;
    ((int4*)cursor)[base_idx] = o;
}

// place: each point claims a unique sorted slot p; writes a full-channel
// pre-weighted record pxv[p] = {w*x[c][k]}_{c=0..15} (128 B = 2 full lines,
// scattered but no write amplification) + pre-bit-reversed column pcol[p].
__global__ __launch_bounds__(256) void place_kernel(const int* __restrict__ cell,
                                                    const float* __restrict__ sdcf,
                                                    int* __restrict__ cursor,
                                                    int* __restrict__ pcol,
                                                    float2* __restrict__ pxv,
                                                    const float* __restrict__ xr,
                                                    const float* __restrict__ xi) {
    int k = blockIdx.x * 256 + threadIdx.x;
    int cl = cell[k];
    float w = sdcf[k];
    int p = atomicAdd(&cursor[cl], 1);
    int col = cl & (N - 1);
    pcol[p] = (int)(__brev((unsigned)col) >> (32 - LOG2N));   // bit-reversed col
    float2* rec = pxv + (size_t)p * C;
#pragma unroll
    for (int c = 0; c < C; ++c) {
        rec[c] = make_float2(xr[(size_t)c * K + k] * w, xi[(size_t)c * K + k] * w);
    }
}

// ============ fused grid-build + row FFT: 8 channels per block ============
// block = (row r, half g2). Each point's slice for this block is a contiguous
// 64 B-aligned 64 B read (exactly one cache line -> zero cross-XCD over-fetch).
// LDS: float4 s4[4][N], each float4 = {reA,imA,reB,imB} of a channel pair ->
// ds_read/write_b128 butterflies; one sincos per stage amortized over 8 ch.
__global__ __launch_bounds__(256) void build_rowfft_kernel(const int* __restrict__ offs,
                                                           const int* __restrict__ pcol,
                                                           const float2* __restrict__ pxv,
                                                           float2* __restrict__ grid) {
    __shared__ float4 s4[4][N];          // 32 KB
    int b = blockIdx.x;
    int g2 = b & 1;                      // which 8-channel half
    int r = b >> 1;
    int t = threadIdx.x;

    for (int i = t; i < N; i += 256) {
        s4[0][i] = make_float4(0.f, 0.f, 0.f, 0.f);
        s4[1][i] = make_float4(0.f, 0.f, 0.f, 0.f);
        s4[2][i] = make_float4(0.f, 0.f, 0.f, 0.f);
        s4[3][i] = make_float4(0.f, 0.f, 0.f, 0.f);
    }
    int start = offs[r * N];
    int end   = offs[r * N + N];         // r=511 uses offs[NN]=K
    __syncthreads();

    // point-parallel streaming scatter: one 64 B line per point
    const f4* pxv4 = (const f4*)pxv;     // record = 8 x f4
    for (int p = start + t; p < end; p += 256) {
        int bc = pcol[p];
        const f4* rec = pxv4 + (size_t)p * 8 + g2 * 4;
#pragma unroll
        for (int g = 0; g < 4; ++g) {
            f4 v = __builtin_nontemporal_load(rec + g);
            atomicAdd(&s4[g][bc].x, v.x);
            atomicAdd(&s4[g][bc].y, v.y);
            atomicAdd(&s4[g][bc].z, v.z);
            atomicAdd(&s4[g][bc].w, v.w);
        }
    }
    __syncthreads();

    // 9 radix-2 DIT stages, +i exponent; input bit-reversed, output natural
    for (int s = 1; s <= LOG2N; ++s) {
        int half = 1 << (s - 1);
        int m = half << 1;
        int j = t & (half - 1);
        int grp = t >> (s - 1);
        int p1 = grp * m + j;
        int p2 = p1 + half;
        float ang = 6.283185307179586f * (float)j / (float)m;
        float sn, cs;
        __sincosf(ang, &sn, &cs);
#pragma unroll
        for (int g = 0; g < 4; ++g) {
            float4 u = s4[g][p1];
            float4 v = s4[g][p2];
            float tra = cs * v.x - sn * v.y;
            float tia = cs * v.y + sn * v.x;
            float trb = cs * v.z - sn * v.w;
            float tib = cs * v.w + sn * v.z;
            s4[g][p2] = make_float4(u.x - tra, u.y - tia, u.z - trb, u.w - tib);
            s4[g][p1] = make_float4(u.x + tra, u.y + tia, u.z + trb, u.w + tib);
        }
        __syncthreads();
    }

#pragma unroll
    for (int g = 0; g < 4; ++g) {
        int ca = g2 * 8 + 2 * g;
        float2* ga = grid + (size_t)ca * NN + (size_t)r * N;
        float2* gb = grid + (size_t)(ca + 1) * NN + (size_t)r * N;
        for (int i = t; i < N; i += 256) {
            float4 v = s4[g][i];
            ga[i] = make_float2(v.x, v.y);
            gb[i] = make_float2(v.z, v.w);
        }
    }
}

// ============ column FFT: NCOL columns per block through LDS ============
__global__ __launch_bounds__(256) void colfft_kernel(float2* __restrict__ grid) {
    __shared__ float sr[N * NCOL];
    __shared__ float si[N * NCOL];
    int blk = blockIdx.x;                        // c * (N/NCOL) + cg
    int c = blk >> 6;
    int cg = blk & 63;
    float2* base = grid + (size_t)c * NN + cg * NCOL;
    int t = threadIdx.x;

    for (int e = t; e < N * NCOL; e += 256) {
        int row = e >> 3, col = e & 7;
        float2 v = base[(size_t)row * N + col];
        sr[e] = v.x; si[e] = v.y;
    }
    __syncthreads();

    int col = t & 7;
    int tg = t >> 3;
    for (int i = tg; i < N; i += 32) {
        int j = __brev((unsigned)i) >> (32 - LOG2N);
        if (j > i) {
            int a1 = i * NCOL + col, a2 = j * NCOL + col;
            float a = sr[a1]; sr[a1] = sr[a2]; sr[a2] = a;
            float b = si[a1]; si[a1] = si[a2]; si[a2] = b;
        }
    }
    __syncthreads();

    for (int s = 1; s <= LOG2N; ++s) {
        int half = 1 << (s - 1);
        int m = half << 1;
        for (int b = tg; b < 256; b += 32) {
            int j = b & (half - 1);
            int grp = b >> (s - 1);
            int p1 = grp * m + j;
            int p2 = p1 + half;
            float ang = 6.283185307179586f * (float)j / (float)m;
            float sn, cs;
            __sincosf(ang, &sn, &cs);
            int a1 = p1 * NCOL + col, a2 = p2 * NCOL + col;
            float xr2 = sr[a2], xi2 = si[a2];
            float tr = cs * xr2 - sn * xi2;
            float ti = cs * xi2 + sn * xr2;
            float ur = sr[a1], ui = si[a1];
            sr[a2] = ur - tr; si[a2] = ui - ti;
            sr[a1] = ur + tr; si[a1] = ui + ti;
        }
        __syncthreads();
    }

    for (int e = t; e < N * NCOL; e += 256) {
        int row = e >> 3, col2 = e & 7;
        base[(size_t)row * N + col2] = make_float2(sr[e], si[e]);
    }
}

// ============ combine: out = (-1)^(ny+nx) * sum_c conj(csm)*img ============
__global__ __launch_bounds__(256) void combine_kernel(const float* __restrict__ csr,
                                                      const float* __restrict__ csi,
                                                      const float2* __restrict__ grid,
                                                      float* __restrict__ out) {
    int pix = blockIdx.x * 256 + threadIdx.x;
    int ny = pix >> LOG2N, nx = pix & (N - 1);
    float ar = 0.f, ai = 0.f;
#pragma unroll
    for (int c = 0; c < C; ++c) {
        float2 uv = grid[(size_t)c * NN + pix];
        float a = csr[c * NN + pix];
        float b = csi[c * NN + pix];
        ar += a * uv.x + b * uv.y;
        ai += a * uv.y - b * uv.x;
    }
    float s = ((ny + nx) & 1) ? -1.f : 1.f;      // fftshift folded into output sign
    out[pix] = s * ar;
    out[NN + pix] = s * ai;
}

extern "C" void kernel_launch(void* const* d_in, const int* in_sizes, int n_in,
                              void* d_out, int out_size, void* d_ws, size_t ws_size,
                              hipStream_t stream) {
    const float* x_real   = (const float*)d_in[0];
    const float* x_imag   = (const float*)d_in[1];
    const float* csm_real = (const float*)d_in[2];
    const float* csm_imag = (const float*)d_in[3];
    const float2* traj    = (const float2*)d_in[4];
    const float* dcf      = (const float*)d_in[5];
    float* out = (float*)d_out;

    char* ws = (char*)d_ws;
    size_t o = 0;
    float* grid  = (float*)(ws + o); o += (size_t)C * NN * 2 * sizeof(float);  // 32 MB
    float2* pxv  = (float2*)(ws + o); o += (size_t)K * C * sizeof(float2);     // 32 MB
    int*   cell  = (int*)(ws + o);   o += (size_t)K * sizeof(int);             // 1 MB
    float* sdcf  = (float*)(ws + o); o += (size_t)K * sizeof(float);           // 1 MB
    int*   count = (int*)(ws + o);   o += (size_t)NN * sizeof(int);            // 1 MB
    int*   offs  = (int*)(ws + o);   o += ((size_t)NN + 4) * sizeof(int);      // 1 MB (+pad)
    int*   cursor= (int*)(ws + o);   o += (size_t)NN * sizeof(int);            // 1 MB
    int*   pcol  = (int*)(ws + o);   o += (size_t)K * sizeof(int);             // 1 MB
    int*   bsum  = (int*)(ws + o);   o += 256 * sizeof(int);
    int*   boffs = (int*)(ws + o);   o += 256 * sizeof(int);

    (void)hipMemsetAsync(count, 0, (size_t)NN * sizeof(int), stream);

    prep_hist_kernel<<<K / 256, 256, 0, stream>>>(traj, dcf, cell, sdcf, count);
    scan_reduce_kernel<<<256, 256, 0, stream>>>(count, bsum);
    scan_top_kernel<<<1, 256, 0, stream>>>(bsum, boffs, offs);
    scan_final_kernel<<<256, 256, 0, stream>>>(count, boffs, offs, cursor);
    place_kernel<<<K / 256, 256, 0, stream>>>(cell, sdcf, cursor, pcol, pxv, x_real, x_imag);
    build_rowfft_kernel<<<N * 2, 256, 0, stream>>>(offs, pcol, pxv, (float2*)grid);
    colfft_kernel<<<C * (N / NCOL), 256, 0, stream>>>((float2*)grid);
    combine_kernel<<<NN / 256, 256, 0, stream>>>(csm_real, csm_imag, (float2*)grid, out);
}

// Round 10
// 248.156 us; speedup vs baseline: 1.0427x; 1.0086x over previous
//
#include <hip/hip_runtime.h>
#include <math.h>

#define N 512
#define NN (N * N)
#define C 16
#define K 262144
#define LOG2N 9
#define NCOL 8

typedef float f4 __attribute__((ext_vector_type(4)));

// ============ phase 1: bin points by cell (counting sort, no fp atomics) ============

__global__ __launch_bounds__(256) void prep_hist_kernel(const float2* __restrict__ traj,
                                                        const float* __restrict__ dcf,
                                                        int* __restrict__ cell,
                                                        float* __restrict__ sdcf,
                                                        int* __restrict__ count) {
    int k = blockIdx.x * 256 + threadIdx.x;
    float2 t = traj[k];
    // jnp.round is half-to-even; __float2int_rn matches.
    int iy = __float2int_rn((t.x + 0.5f) * (float)N) & (N - 1);
    int ix = __float2int_rn((t.y + 0.5f) * (float)N) & (N - 1);
    int cl = iy * N + ix;
    cell[k] = cl;
    float s = ((iy + ix) & 1) ? -1.0f : 1.0f;   // ifftshift folded into input sign
    sdcf[k] = dcf[k] * s;
    atomicAdd(&count[cl], 1);                    // avg 1 pt/cell -> low contention
}

__global__ __launch_bounds__(256) void scan_reduce_kernel(const int* __restrict__ count,
                                                          int* __restrict__ bsum) {
    __shared__ int sd[256];
    int t = threadIdx.x;
    const int4* c4 = (const int4*)count;
    int4 v = c4[blockIdx.x * 256 + t];
    sd[t] = v.x + v.y + v.z + v.w;
    __syncthreads();
    for (int d = 128; d > 0; d >>= 1) {
        if (t < d) sd[t] += sd[t + d];
        __syncthreads();
    }
    if (t == 0) bsum[blockIdx.x] = sd[0];
}

__global__ __launch_bounds__(256) void scan_top_kernel(const int* __restrict__ bsum,
                                                       int* __restrict__ boffs,
                                                       int* __restrict__ offs) {
    __shared__ int sd[256];
    int t = threadIdx.x;
    int v = bsum[t];
    sd[t] = v;
    __syncthreads();
    for (int d = 1; d < 256; d <<= 1) {
        int tmp = (t >= d) ? sd[t - d] : 0;
        __syncthreads();
        sd[t] += tmp;
        __syncthreads();
    }
    boffs[t] = sd[t] - v;   // exclusive
    if (t == 0) offs[NN] = K;
}

__global__ __launch_bounds__(256) void scan_final_kernel(const int* __restrict__ count,
                                                         const int* __restrict__ boffs,
                                                         int* __restrict__ offs,
                                                         int* __restrict__ cursor) {
    __shared__ int sd[256];
    int t = threadIdx.x;
    int base_idx = blockIdx.x * 256 + t;
    const int4* c4 = (const int4*)count;
    int4 v = c4[base_idx];
    int s = v.x + v.y + v.z + v.w;
    sd[t] = s;
    __syncthreads();
    for (int d = 1; d < 256; d <<= 1) {
        int tmp = (t >= d) ? sd[t - d] : 0;
        __syncthreads();
        sd[t] += tmp;
        __syncthreads();
    }
    int base = boffs[blockIdx.x] + sd[t] - s;    // global exclusive prefix for this thread's 4
    int4 o;
    o.x = base;
    o.y = base + v.x;
    o.z = base + v.x + v.y;
    o.w = base + v.x + v.y + v.z;
    ((int4*)offs)[base_idx] = o;
    ((int4*)cursor)[base_idx] = o;
}

// place: each point claims a unique sorted slot p; writes a full-channel
// pre-weighted record pxv[p] = {w*x[c][k]}_{c=0..15} (128 B = 2 full lines,
// scattered but no write amplification) + pre-bit-reversed column pcol[p].
__global__ __launch_bounds__(256) void place_kernel(const int* __restrict__ cell,
                                                    const float* __restrict__ sdcf,
                                                    int* __restrict__ cursor,
                                                    int* __restrict__ pcol,
                                                    float2* __restrict__ pxv,
                                                    const float* __restrict__ xr,
                                                    const float* __restrict__ xi) {
    int k = blockIdx.x * 256 + threadIdx.x;
    int cl = cell[k];
    float w = sdcf[k];
    int p = atomicAdd(&cursor[cl], 1);
    int col = cl & (N - 1);
    pcol[p] = (int)(__brev((unsigned)col) >> (32 - LOG2N));   // bit-reversed col
    float2* rec = pxv + (size_t)p * C;
#pragma unroll
    for (int c = 0; c < C; ++c) {
        rec[c] = make_float2(xr[(size_t)c * K + k] * w, xi[(size_t)c * K + k] * w);
    }
}

// ============ fused grid-build + row FFT: 8 channels per block, radix-2^2 ============
// block = (row r, half g2), 512 threads (8 waves -> 32 waves/CU, 100% occ cap).
// Scatter: each point's slice = one 64 B line (zero cross-XCD over-fetch).
// FFT: fused radix-2^2 stages (1,2),(3,4),(5,6),(7,8) + final radix-2 stage 9
// -> 5 barriers instead of 9, LDS traffic halved. Input pre-bit-reversed.
__global__ __launch_bounds__(512) void build_rowfft_kernel(const int* __restrict__ offs,
                                                           const int* __restrict__ pcol,
                                                           const float2* __restrict__ pxv,
                                                           float2* __restrict__ grid) {
    __shared__ float4 s4[4][N];          // 32 KB; float4 = {reA,imA,reB,imB} of a channel pair
    int b = blockIdx.x;
    int g2 = b & 1;                      // which 8-channel half
    int r = b >> 1;
    int t = threadIdx.x;

    {
        float4* sflat = (float4*)s4;
        for (int i = t; i < 4 * N; i += 512) sflat[i] = make_float4(0.f, 0.f, 0.f, 0.f);
    }
    int start = offs[r * N];
    int end   = offs[r * N + N];         // r=511 uses offs[NN]=K
    __syncthreads();

    // point-parallel streaming scatter: one 64 B line per point
    const f4* pxv4 = (const f4*)pxv;     // record = 8 x f4
    for (int p = start + t; p < end; p += 512) {
        int bc = pcol[p];
        const f4* rec = pxv4 + (size_t)p * 8 + g2 * 4;
#pragma unroll
        for (int g = 0; g < 4; ++g) {
            f4 v = __builtin_nontemporal_load(rec + g);
            atomicAdd(&s4[g][bc].x, v.x);
            atomicAdd(&s4[g][bc].y, v.y);
            atomicAdd(&s4[g][bc].z, v.z);
            atomicAdd(&s4[g][bc].w, v.w);
        }
    }
    __syncthreads();

    // fused radix-2^2: stages (s,s+1) for s=1,3,5,7. Thread owns one
    // (butterfly u, channel-group g) unit: 128 butterflies x 4 groups = 512.
    int g = t >> 7;                      // 0..3
    int u = t & 127;                     // butterfly within group
    for (int s = 1; s <= 7; s += 2) {
        int h = 1 << (s - 1);
        int j = u & (h - 1);
        int grp = u >> (s - 1);
        int p0 = grp * 4 * h + j;
        float th = 6.283185307179586f * (float)j / (float)(2 * h);
        float sW, cW, sV, cV;
        __sincosf(th, &sW, &cW);          // W = stage-s twiddle
        __sincosf(th * 0.5f, &sV, &cV);   // V = stage-(s+1) twiddle
        float4 A = s4[g][p0];
        float4 B = s4[g][p0 + h];
        float4 Cc = s4[g][p0 + 2 * h];
        float4 D = s4[g][p0 + 3 * h];
        // stage s: (A,B) and (C,D) with W
        float bx = cW * B.x - sW * B.y, by = cW * B.y + sW * B.x;
        float bz = cW * B.z - sW * B.w, bw = cW * B.w + sW * B.z;
        float4 A1 = make_float4(A.x + bx, A.y + by, A.z + bz, A.w + bw);
        float4 B1 = make_float4(A.x - bx, A.y - by, A.z - bz, A.w - bw);
        float dx = cW * D.x - sW * D.y, dy = cW * D.y + sW * D.x;
        float dz = cW * D.z - sW * D.w, dw = cW * D.w + sW * D.z;
        float4 C1 = make_float4(Cc.x + dx, Cc.y + dy, Cc.z + dz, Cc.w + dw);
        float4 D1 = make_float4(Cc.x - dx, Cc.y - dy, Cc.z - dz, Cc.w - dw);
        // stage s+1: (A1,C1) with V; (B1,D1) with i*V
        float cx = cV * C1.x - sV * C1.y, cy = cV * C1.y + sV * C1.x;
        float cz = cV * C1.z - sV * C1.w, cw = cV * C1.w + sV * C1.z;
        s4[g][p0]         = make_float4(A1.x + cx, A1.y + cy, A1.z + cz, A1.w + cw);
        s4[g][p0 + 2 * h] = make_float4(A1.x - cx, A1.y - cy, A1.z - cz, A1.w - cw);
        float ex = cV * D1.x - sV * D1.y, ey = cV * D1.y + sV * D1.x;
        float ez = cV * D1.z - sV * D1.w, ew = cV * D1.w + sV * D1.z;
        // i*(ex+i ey) = (-ey, ex)
        s4[g][p0 + h]     = make_float4(B1.x - ey, B1.y + ex, B1.z - ew, B1.w + ez);
        s4[g][p0 + 3 * h] = make_float4(B1.x + ey, B1.y - ex, B1.z + ew, B1.w - ez);
        __syncthreads();
    }

    // final radix-2 stage (s=9, half=256): 1024 units, 2 per thread
    {
        int bb = t & 255;
        int gg = t >> 8;                 // 0..1
        float th = 6.283185307179586f * (float)bb / 512.0f;
        float sn, cs;
        __sincosf(th, &sn, &cs);
#pragma unroll
        for (int gi = 0; gi < 2; ++gi) {
            int g9 = gg + 2 * gi;
            float4 uu = s4[g9][bb];
            float4 vv = s4[g9][bb + 256];
            float tra = cs * vv.x - sn * vv.y;
            float tia = cs * vv.y + sn * vv.x;
            float trb = cs * vv.z - sn * vv.w;
            float tib = cs * vv.w + sn * vv.z;
            s4[g9][bb + 256] = make_float4(uu.x - tra, uu.y - tia, uu.z - trb, uu.w - tib);
            s4[g9][bb]       = make_float4(uu.x + tra, uu.y + tia, uu.z + trb, uu.w + tib);
        }
        __syncthreads();
    }

#pragma unroll
    for (int g4 = 0; g4 < 4; ++g4) {
        int ca = g2 * 8 + 2 * g4;
        float2* ga = grid + (size_t)ca * NN + (size_t)r * N;
        float2* gb = grid + (size_t)(ca + 1) * NN + (size_t)r * N;
        for (int i = t; i < N; i += 512) {
            float4 v = s4[g4][i];
            ga[i] = make_float2(v.x, v.y);
            gb[i] = make_float2(v.z, v.w);
        }
    }
}

// ============ column FFT: NCOL columns per block through LDS ============
__global__ __launch_bounds__(256) void colfft_kernel(float2* __restrict__ grid) {
    __shared__ float sr[N * NCOL];
    __shared__ float si[N * NCOL];
    int blk = blockIdx.x;                        // c * (N/NCOL) + cg
    int c = blk >> 6;
    int cg = blk & 63;
    float2* base = grid + (size_t)c * NN + cg * NCOL;
    int t = threadIdx.x;

    for (int e = t; e < N * NCOL; e += 256) {
        int row = e >> 3, col = e & 7;
        float2 v = base[(size_t)row * N + col];
        sr[e] = v.x; si[e] = v.y;
    }
    __syncthreads();

    int col = t & 7;
    int tg = t >> 3;
    for (int i = tg; i < N; i += 32) {
        int j = __brev((unsigned)i) >> (32 - LOG2N);
        if (j > i) {
            int a1 = i * NCOL + col, a2 = j * NCOL + col;
            float a = sr[a1]; sr[a1] = sr[a2]; sr[a2] = a;
            float b = si[a1]; si[a1] = si[a2]; si[a2] = b;
        }
    }
    __syncthreads();

    for (int s = 1; s <= LOG2N; ++s) {
        int half = 1 << (s - 1);
        int m = half << 1;
        for (int b = tg; b < 256; b += 32) {
            int j = b & (half - 1);
            int grp = b >> (s - 1);
            int p1 = grp * m + j;
            int p2 = p1 + half;
            float ang = 6.283185307179586f * (float)j / (float)m;
            float sn, cs;
            __sincosf(ang, &sn, &cs);
            int a1 = p1 * NCOL + col, a2 = p2 * NCOL + col;
            float xr2 = sr[a2], xi2 = si[a2];
            float tr = cs * xr2 - sn * xi2;
            float ti = cs * xi2 + sn * xr2;
            float ur = sr[a1], ui = si[a1];
            sr[a2] = ur - tr; si[a2] = ui - ti;
            sr[a1] = ur + tr; si[a1] = ui + ti;
        }
        __syncthreads();
    }

    for (int e = t; e < N * NCOL; e += 256) {
        int row = e >> 3, col2 = e & 7;
        base[(size_t)row * N + col2] = make_float2(sr[e], si[e]);
    }
}

// ============ combine: out = (-1)^(ny+nx) * sum_c conj(csm)*img ============
__global__ __launch_bounds__(256) void combine_kernel(const float* __restrict__ csr,
                                                      const float* __restrict__ csi,
                                                      const float2* __restrict__ grid,
                                                      float* __restrict__ out) {
    int pix = blockIdx.x * 256 + threadIdx.x;
    int ny = pix >> LOG2N, nx = pix & (N - 1);
    float ar = 0.f, ai = 0.f;
#pragma unroll
    for (int c = 0; c < C; ++c) {
        float2 uv = grid[(size_t)c * NN + pix];
        float a = csr[c * NN + pix];
        float b = csi[c * NN + pix];
        ar += a * uv.x + b * uv.y;
        ai += a * uv.y - b * uv.x;
    }
    float s = ((ny + nx) & 1) ? -1.f : 1.f;      // fftshift folded into output sign
    out[pix] = s * ar;
    out[NN + pix] = s * ai;
}

extern "C" void kernel_launch(void* const* d_in, const int* in_sizes, int n_in,
                              void* d_out, int out_size, void* d_ws, size_t ws_size,
                              hipStream_t stream) {
    const float* x_real   = (const float*)d_in[0];
    const float* x_imag   = (const float*)d_in[1];
    const float* csm_real = (const float*)d_in[2];
    const float* csm_imag = (const float*)d_in[3];
    const float2* traj    = (const float2*)d_in[4];
    const float* dcf      = (const float*)d_in[5];
    float* out = (float*)d_out;

    char* ws = (char*)d_ws;
    size_t o = 0;
    float* grid  = (float*)(ws + o); o += (size_t)C * NN * 2 * sizeof(float);  // 32 MB
    float2* pxv  = (float2*)(ws + o); o += (size_t)K * C * sizeof(float2);     // 32 MB
    int*   cell  = (int*)(ws + o);   o += (size_t)K * sizeof(int);             // 1 MB
    float* sdcf  = (float*)(ws + o); o += (size_t)K * sizeof(float);           // 1 MB
    int*   count = (int*)(ws + o);   o += (size_t)NN * sizeof(int);            // 1 MB
    int*   offs  = (int*)(ws + o);   o += ((size_t)NN + 4) * sizeof(int);      // 1 MB (+pad)
    int*   cursor= (int*)(ws + o);   o += (size_t)NN * sizeof(int);            // 1 MB
    int*   pcol  = (int*)(ws + o);   o += (size_t)K * sizeof(int);             // 1 MB
    int*   bsum  = (int*)(ws + o);   o += 256 * sizeof(int);
    int*   boffs = (int*)(ws + o);   o += 256 * sizeof(int);

    (void)hipMemsetAsync(count, 0, (size_t)NN * sizeof(int), stream);

    prep_hist_kernel<<<K / 256, 256, 0, stream>>>(traj, dcf, cell, sdcf, count);
    scan_reduce_kernel<<<256, 256, 0, stream>>>(count, bsum);
    scan_top_kernel<<<1, 256, 0, stream>>>(bsum, boffs, offs);
    scan_final_kernel<<<256, 256, 0, stream>>>(count, boffs, offs, cursor);
    place_kernel<<<K / 256, 256, 0, stream>>>(cell, sdcf, cursor, pcol, pxv, x_real, x_imag);
    build_rowfft_kernel<<<N * 2, 512, 0, stream>>>(offs, pcol, pxv, (float2*)grid);
    colfft_kernel<<<C * (N / NCOL), 256, 0, stream>>>((float2*)grid);
    combine_kernel<<<NN / 256, 256, 0, stream>>>(csm_real, csm_imag, (float2*)grid, out);
}